// Round 4
// baseline (6074.715 us; speedup 1.0000x reference)
//
#include <hip/hip_runtime.h>
#include <math.h>

#define NB    8
#define NE    1024
#define DDIM  256
#define TTOK  4096
#define BBATCH 16
#define NTOK  (BBATCH*TTOK)   // 65536

#define TM    64     // tokens per block
#define TN    128    // codes per tile
#define KB    16     // k-chunk
#define CSTR  20     // codes LDS stride (floats)

// ---------- h[c] = 0.5*sum(e*e) with numpy pairwise-sum semantics ----------
// n=256 -> two 128-blocks; each: 8 accumulators r[j] over k = j, j+8, ..., j+120
// (sequential adds), tree-combined ((r0+r1)+(r2+r3))+((r4+r5)+(r6+r7));
// halves added, then * 0.5f. asm barrier prevents mul+add FMA contraction.
__global__ void hsum_kernel(const float* __restrict__ books, float* __restrict__ hg) {
    int c = blockIdx.x * blockDim.x + threadIdx.x;
    if (c >= NB * NE) return;
    const float* e = books + (size_t)c * DDIM;
    float blk[2];
    for (int half = 0; half < 2; ++half) {
        const float* a = e + half * 128;
        float r[8];
        #pragma unroll
        for (int j = 0; j < 8; ++j) {
            float s = a[j] * a[j];
            asm volatile("" : "+v"(s));
            r[j] = s;
        }
        for (int i = 8; i < 128; i += 8) {
            #pragma unroll
            for (int j = 0; j < 8; ++j) {
                float s = a[i + j] * a[i + j];
                asm volatile("" : "+v"(s));
                r[j] = r[j] + s;
            }
        }
        blk[half] = ((r[0] + r[1]) + (r[2] + r[3])) + ((r[4] + r[5]) + (r[6] + r[7]));
    }
    hg[c] = 0.5f * (blk[0] + blk[1]);
}

// ---------- z (B,D,T) -> zt[token][dim] (exact copy/transpose) ----------
__global__ void txin_kernel(const float* __restrict__ z, float* __restrict__ zt) {
    __shared__ float ld[64 * 68];                 // [d][t], stride 68
    int t0 = blockIdx.x * 64, d0 = blockIdx.y * 64, b = blockIdx.z;
    int tid = threadIdx.x;
    {
        int dd = tid >> 2, t4 = (tid & 3) * 16;
        const float* zp = z + ((size_t)b * DDIM + d0 + dd) * TTOK + t0 + t4;
        #pragma unroll
        for (int c = 0; c < 16; c += 4)
            *(float4*)&ld[dd * 68 + t4 + c] = *(const float4*)(zp + c);
    }
    __syncthreads();
    {
        int t = tid >> 2, d4 = (tid & 3) * 16;
        float* rp = zt + ((size_t)b * TTOK + t0 + t) * DDIM + d0 + d4;
        #pragma unroll
        for (int c = 0; c < 16; c += 4) {
            float4 o;
            o.x = ld[(size_t)(d4 + c + 0) * 68 + t];
            o.y = ld[(size_t)(d4 + c + 1) * 68 + t];
            o.z = ld[(size_t)(d4 + c + 2) * 68 + t];
            o.w = ld[(size_t)(d4 + c + 3) * 68 + t];
            *(float4*)(rp + c) = o;
        }
    }
}

// ---------- main: fp32 scan matching numpy sgemm bit-for-bit ----------
// score dot: sequential-k fmaf chain from 0.0f, then a single subtract of h.
__launch_bounds__(256)
__global__ void vq_main(const float* __restrict__ books,
                        const float* __restrict__ hg,
                        const float* __restrict__ zt,
                        int* __restrict__ idxg) {
    __shared__ float res_s[TM * DDIM];    // 64 KB residual (fp32, exact chain)
    __shared__ float cs[TN * CSTR];       // 10 KB code tile
    __shared__ float h_s[NE];             // 4 KB
    __shared__ int   bidx_s[TM];

    const int tid  = threadIdx.x;
    const int tx   = tid & 31;
    const int ty   = tid >> 5;
    const int wave = tid >> 6;
    const int lane = tid & 63;
    const size_t tok0 = (size_t)blockIdx.x * TM;

    for (int tt = 0; tt < 16; ++tt) {
        int m = tt * 4 + wave;
        *(float4*)&res_s[m * DDIM + lane * 4] =
            *(const float4*)&zt[(tok0 + m) * DDIM + lane * 4];
    }

    for (int book = 0; book < NB; ++book) {
        const float* cb = books + (size_t)book * NE * DDIM;
        *(float4*)&h_s[tid * 4] = *(const float4*)&hg[book * NE + tid * 4];

        float bv[8]; int bn[8];
        #pragma unroll
        for (int j = 0; j < 8; ++j) { bv[j] = -3.4e38f; bn[j] = 0; }

        for (int ct = 0; ct < NE / TN; ++ct) {
            const int n0 = ct * TN;
            float acc[8][4];
            #pragma unroll
            for (int j = 0; j < 8; ++j)
                #pragma unroll
                for (int i = 0; i < 4; ++i) acc[j][i] = 0.0f;

            for (int kc = 0; kc < DDIM / KB; ++kc) {
                const int k0 = kc * KB;
                __syncthreads();
                {   // stage 128 codes x 16 k
                    int code = tid >> 1, kh = (tid & 1) * 8;
                    const float* g = cb + (size_t)(n0 + code) * DDIM + k0 + kh;
                    float4 c0 = ((const float4*)g)[0];
                    float4 c1 = ((const float4*)g)[1];
                    *(float4*)&cs[code * CSTR + kh]     = c0;
                    *(float4*)&cs[code * CSTR + kh + 4] = c1;
                }
                __syncthreads();
                #pragma unroll
                for (int k4 = 0; k4 < KB; k4 += 4) {
                    float4 rv[8], cv[4];
                    #pragma unroll
                    for (int j = 0; j < 8; ++j)
                        rv[j] = *(const float4*)&res_s[(ty * 8 + j) * DDIM + k0 + k4];
                    #pragma unroll
                    for (int i = 0; i < 4; ++i)
                        cv[i] = *(const float4*)&cs[(tx + 32 * i) * CSTR + k4];
                    // strict k-ascending single-accumulator fmaf chain (matches sgemm)
                    #pragma unroll
                    for (int j = 0; j < 8; ++j)
                        #pragma unroll
                        for (int i = 0; i < 4; ++i) {
                            float a = acc[j][i];
                            a = __builtin_fmaf(rv[j].x, cv[i].x, a);
                            a = __builtin_fmaf(rv[j].y, cv[i].y, a);
                            a = __builtin_fmaf(rv[j].z, cv[i].z, a);
                            a = __builtin_fmaf(rv[j].w, cv[i].w, a);
                            acc[j][i] = a;
                        }
                }
            }
            // score = dot - h (single subtract, as numpy broadcasts after the gemm);
            // candidates visited in ascending n -> strict '>' keeps first occurrence
            #pragma unroll
            for (int i = 0; i < 4; ++i) {
                int n = n0 + tx + 32 * i;
                float hh = h_s[n];
                #pragma unroll
                for (int j = 0; j < 8; ++j) {
                    float v = acc[j][i] - hh;
                    if (v > bv[j]) { bv[j] = v; bn[j] = n; }
                }
            }
        }
        // cross-tx butterfly argmax (masks <32 stay within each 32-lane half)
        #pragma unroll
        for (int j = 0; j < 8; ++j) {
            float v = bv[j]; int n = bn[j];
            #pragma unroll
            for (int m5 = 16; m5; m5 >>= 1) {
                float ov = __shfl_xor(v, m5, 64);
                int   on = __shfl_xor(n, m5, 64);
                if (ov > v || (ov == v && on < n)) { v = ov; n = on; }
            }
            if (tx == 0) bidx_s[ty * 8 + j] = n;
        }
        __syncthreads();
        if (tid < TM) idxg[(tok0 + tid) * NB + book] = bidx_s[tid];
        // residual update: r = r - q, plain fp32 subs (matches reference chain)
        for (int tt = 0; tt < 16; ++tt) {
            int m = tt * 4 + wave;
            int idx = bidx_s[m];
            float4 q = *(const float4*)&cb[(size_t)idx * DDIM + lane * 4];
            float4 r = *(float4*)&res_s[m * DDIM + lane * 4];
            r.x = r.x - q.x; r.y = r.y - q.y; r.z = r.z - q.z; r.w = r.w - q.w;
            *(float4*)&res_s[m * DDIM + lane * 4] = r;
        }
        __syncthreads();
    }
}

// ---------- replay: q_sum with the reference's exact fp32 op order ----------
// per element: t1 = q - r; qs = qs + t1; qs = qs + r; r = r - q   (all fp32)
__global__ void replay_kernel(const float* __restrict__ books,
                              const int* __restrict__ idxg,
                              float* __restrict__ zt) {
    size_t gid = (size_t)blockIdx.x * 256 + threadIdx.x;   // token*64 + dim-group
    size_t tok = gid >> 6;
    int d4 = (int)(gid & 63) * 4;
    const int* ip = idxg + tok * NB;
    float4 r = *(const float4*)&zt[tok * DDIM + d4];
    float4 qs = make_float4(0.f, 0.f, 0.f, 0.f);
    #pragma unroll
    for (int b = 0; b < NB; ++b) {
        int idx = ip[b];
        float4 q = *(const float4*)&books[((size_t)b * NE + idx) * DDIM + d4];
        float t1;
        t1 = q.x - r.x; qs.x = qs.x + t1; qs.x = qs.x + r.x; r.x = r.x - q.x;
        t1 = q.y - r.y; qs.y = qs.y + t1; qs.y = qs.y + r.y; r.y = r.y - q.y;
        t1 = q.z - r.z; qs.z = qs.z + t1; qs.z = qs.z + r.z; r.z = r.z - q.z;
        t1 = q.w - r.w; qs.w = qs.w + t1; qs.w = qs.w + r.w; r.w = r.w - q.w;
    }
    *(float4*)&zt[tok * DDIM + d4] = qs;   // overwrite in place (own element)
}

// ---------- out (B,D,T) = transpose of q_sum[token][dim] ----------
__global__ void fin_kernel(const float* __restrict__ qst, float* __restrict__ out) {
    __shared__ float ld[64 * 68];                 // [t][d], stride 68
    int t0 = blockIdx.x * 64, d0 = blockIdx.y * 64, b = blockIdx.z;
    int tid = threadIdx.x;
    {
        int t = tid >> 2, d4 = (tid & 3) * 16;
        const float* rp = qst + ((size_t)b * TTOK + t0 + t) * DDIM + d0 + d4;
        #pragma unroll
        for (int c = 0; c < 16; c += 4)
            *(float4*)&ld[t * 68 + d4 + c] = *(const float4*)(rp + c);
    }
    __syncthreads();
    {
        int dd = tid >> 2, t4 = (tid & 3) * 16;
        float* op = out + ((size_t)b * DDIM + d0 + dd) * TTOK + t0 + t4;
        #pragma unroll
        for (int c = 0; c < 16; c += 4) {
            float4 o;
            o.x = ld[(size_t)(t4 + c + 0) * 68 + dd];
            o.y = ld[(size_t)(t4 + c + 1) * 68 + dd];
            o.z = ld[(size_t)(t4 + c + 2) * 68 + dd];
            o.w = ld[(size_t)(t4 + c + 3) * 68 + dd];
            *(float4*)(op + c) = o;
        }
    }
}

extern "C" void kernel_launch(void* const* d_in, const int* in_sizes, int n_in,
                              void* d_out, int out_size, void* d_ws, size_t ws_size,
                              hipStream_t stream) {
    const float* z     = (const float*)d_in[0];
    const float* books = (const float*)d_in[1];
    float* out = (float*)d_out;

    float* hg   = (float*)d_ws;                          // 8192 floats
    int*   idxg = (int*)(hg + (size_t)NB * NE);          // 65536*8 ints (2 MB)
    float* zt   = (float*)(idxg + (size_t)NTOK * NB);    // 64 MB token-major

    hsum_kernel<<<(NB * NE + 255) / 256, 256, 0, stream>>>(books, hg);
    txin_kernel<<<dim3(TTOK / 64, DDIM / 64, BBATCH), 256, 0, stream>>>(z, zt);
    vq_main<<<NTOK / TM, 256, 0, stream>>>(books, hg, zt, idxg);
    replay_kernel<<<NTOK * 64 / 256, 256, 0, stream>>>(books, idxg, zt);
    fin_kernel<<<dim3(TTOK / 64, DDIM / 64, BBATCH), 256, 0, stream>>>(zt, out);
}